// Round 6
// baseline (145.134 us; speedup 1.0000x reference)
//
#include <hip/hip_runtime.h>
#include <hip/hip_bf16.h>

// SineLayer: y[b,o] = sum_{i,d} sin(w_d*x[b,i]+p_d) * (scale_d*c[o,i,d]) + offs[o]
// GEMM: M=32768, N=512, K=4096, bf16 MFMA 16x16x32.
// R6: m201-style phase-split. Per K-step, 4 phases: {2 GLL + ds_read quadrant
// + sin-half ; barrier ; lgkmcnt(0) ; setprio(1) 16xMFMA setprio(0) ; barrier}.
// End-of-step: vmcnt(1) (drains the 8 B-GLLs, keeps x-prefetch) + lgkmcnt(0).
// BM=128 x BN=512 (each sin computed once globally), 160 KB LDS.

#define BATCH 32768
#define NIN   256
#define NOUT  512
#define DDIM  16
#define BM    128
#define BN    512
#define BK    64
#define NKT   ((NIN*DDIM)/BK)     // 64 K-steps
#define TILE_BYTES (BN*BK*2)      // 64 KB per kt pre-swizzled B tile
#define ABYTES (BM*BK*2)          // 16 KB per A buffer
#define BBYTES (BN*BK*2)          // 64 KB per B buffer
#define EPSV  1e-8f
#define INV2PI 0.15915494309189535f

typedef short  bf16x8 __attribute__((ext_vector_type(8)));
typedef float  f32x4  __attribute__((ext_vector_type(4)));

static __device__ __forceinline__ ushort f2bf(float f) {
  union { __hip_bfloat16 h; ushort u; } cv;
  cv.h = __float2bfloat16(f);
  return cv.u;
}

static __device__ __forceinline__ float sgpr_f(float v) {
  return __builtin_bit_cast(float,
      __builtin_amdgcn_readfirstlane(__builtin_bit_cast(int, v)));
}

// ---------------------------------------------------------------------------
// Prep: cb[o,k] = bf16(scale_d * c[o,i,d]) as ONE pre-swizzled 512x64 tile per
// kt (byte = (r*128 + kloc*2) ^ ((r&7)<<4), r = o) so a LINEAR global_load_lds
// copy yields the swizzled LDS image. offs[o] = bias[o] + sum mu*scale*c.
// ---------------------------------------------------------------------------
__global__ __launch_bounds__(256) void prep_kernel(
    const float* __restrict__ omega, const float* __restrict__ phase,
    const float* __restrict__ c_basis, const float* __restrict__ bias,
    ushort* __restrict__ cb, float* __restrict__ offs)
{
  __shared__ float s_scale[DDIM];
  __shared__ float s_musc[DDIM];
  __shared__ float s_red[4];

  const int o = blockIdx.x;
  const int t = threadIdx.x;

  if (t < DDIM) {
    float w = omega[t];
    float p = phase[t];
    float mu  = expf(-0.5f * w * w) * sinf(p);
    float var = 0.5f * (1.0f - expf(-2.0f * w * w) * cosf(2.0f * p)) - mu * mu;
    float sd  = sqrtf(fmaxf(var, 0.0f));
    float sc  = 1.0f / (sd + EPSV);
    s_scale[t] = sc;
    s_musc[t]  = mu * sc;
  }
  __syncthreads();

  const float* cp = c_basis + ((size_t)o * NIN + t) * DDIM;
  float cv[DDIM];
  {
    const float4* cp4 = (const float4*)cp;
    float4 a = cp4[0], b = cp4[1], c = cp4[2], d = cp4[3];
    cv[0]=a.x; cv[1]=a.y; cv[2]=a.z; cv[3]=a.w;
    cv[4]=b.x; cv[5]=b.y; cv[6]=b.z; cv[7]=b.w;
    cv[8]=c.x; cv[9]=c.y; cv[10]=c.z; cv[11]=c.w;
    cv[12]=d.x; cv[13]=d.y; cv[14]=d.z; cv[15]=d.w;
  }

  float partial = 0.0f;
  uint pk[8];
#pragma unroll
  for (int d = 0; d < DDIM; d += 2) {
    partial += cv[d] * s_musc[d] + cv[d+1] * s_musc[d+1];
    ushort u0 = f2bf(cv[d]   * s_scale[d]);
    ushort u1 = f2bf(cv[d+1] * s_scale[d+1]);
    pk[d >> 1] = (uint)u0 | ((uint)u1 << 16);
  }

  {
    const int r   = o;               // 0..511
    const int kt  = t >> 2;
    const int swz = (r & 7) << 4;
    char* tile = (char*)cb + (size_t)kt * TILE_BYTES;
    int b0 = r * 128 + (t & 3) * 32;
    *(uint4*)(tile + ((b0     ) ^ swz)) = make_uint4(pk[0], pk[1], pk[2], pk[3]);
    *(uint4*)(tile + ((b0 + 16) ^ swz)) = make_uint4(pk[4], pk[5], pk[6], pk[7]);
  }

#pragma unroll
  for (int off = 32; off > 0; off >>= 1) partial += __shfl_down(partial, off, 64);
  if ((t & 63) == 0) s_red[t >> 6] = partial;
  __syncthreads();
  if (t == 0) offs[o] = bias[o] + s_red[0] + s_red[1] + s_red[2] + s_red[3];
}

// ---------------------------------------------------------------------------
// GEMM: 128x512 tile, BK=64, 512 threads (8 waves: 2m x 4n, wave = 64x128).
// LDS: A0[16K] A1[16K] B0[64K] B1[64K] = 160 KB -> 1 block/CU, 2 waves/SIMD.
// ---------------------------------------------------------------------------
__global__ __launch_bounds__(512, 2) void gemm_kernel(
    const float* __restrict__ x, const float* __restrict__ omega,
    const float* __restrict__ phase, const ushort* __restrict__ cb,
    const float* __restrict__ offs, float* __restrict__ out)
{
  extern __shared__ char lds[];

  const int t    = threadIdx.x;
  const int lane = t & 63;
  const int wid  = t >> 6;
  const int wm   = wid >> 2;       // 0..1
  const int wn   = wid & 3;        // 0..3
  const int row0 = blockIdx.x * BM;

  // uniform omega/phase in SGPRs (readfirstlane) -> zero VGPR cost
  float wv[DDIM], pv[DDIM];
#pragma unroll
  for (int d = 0; d < DDIM; ++d) {
    wv[d] = sgpr_f(omega[d] * INV2PI);
    pv[d] = sgpr_f(phase[d] * INV2PI);
  }

  f32x4 acc[4][8];
#pragma unroll
  for (int m = 0; m < 4; ++m)
#pragma unroll
    for (int n = 0; n < 8; ++n) acc[m][n] = (f32x4){0.f, 0.f, 0.f, 0.f};

  // A staging: thread t -> row t>>2 (0..127), i-slot t&3; 1 x -> 16 sins
  const int arow = t >> 2;
  const int acol = t & 3;
  const float* xbase = x + (size_t)(row0 + arow) * NIN + acol;
  const int aswz = (arow & 7) << 4;
  const int ab0  = arow * 128 + acol * 32;

  const int hi  = lane >> 4;       // 0..3
  const int l15 = lane & 15;

#define GLL(s_, d_) __builtin_amdgcn_global_load_lds(                          \
      (const __attribute__((address_space(1))) void*)(s_),                     \
      (__attribute__((address_space(3))) void*)(d_), 16, 0, 0)

  // quarter of the B-tile staging: 2 global_load_lds (16 KB)
#define ISSUE_B2(kt_, sb_, q_)                                                 \
  {                                                                            \
    const char* src = (const char*)cb + (size_t)(kt_) * TILE_BYTES             \
                      + wid * 8192 + (q_) * 2048 + lane * 16;                  \
    char* dst = lds + 32768 + (sb_) * BBYTES + wid * 8192 + (q_) * 2048;       \
    GLL(src, dst); GLL(src + 1024, dst + 1024);                                \
  }

  // half of the sins: 8 sins -> 4 packed words pk[h*4 .. h*4+3]
#define SINS_HALF(xx_, h_)                                                     \
    _Pragma("unroll")                                                          \
    for (int d = (h_) * 8; d < (h_) * 8 + 8; d += 2) {                         \
      float s0 = __builtin_amdgcn_sinf(fmaf(wv[d],   (xx_), pv[d]));           \
      float s1 = __builtin_amdgcn_sinf(fmaf(wv[d+1], (xx_), pv[d+1]));         \
      uint u0 = __builtin_bit_cast(uint, s0) + 0x8000u;                        \
      uint u1 = __builtin_bit_cast(uint, s1) + 0x8000u;                        \
      pk[d >> 1] = __builtin_amdgcn_perm(u1, u0, 0x07060302u);                 \
    }

#define A_WRITE(h_, sb_)                                                       \
    *(uint4*)(lds + (sb_) * ABYTES + ((ab0 + (h_) * 16) ^ aswz)) =             \
        make_uint4(pk[(h_)*4], pk[(h_)*4+1], pk[(h_)*4+2], pk[(h_)*4+3]);

#define LOAD_AF(kk_)                                                           \
    _Pragma("unroll")                                                          \
    for (int m = 0; m < 4; ++m) {                                              \
      int rr = wm * 64 + m * 16 + l15;                                         \
      af[m] = *(const bf16x8*)(AsB + ((rr*128 + (kk_)*64 + hi*16) ^ ((rr&7)<<4))); \
    }

#define LOAD_BF(kk_, nh_)                                                      \
    _Pragma("unroll")                                                          \
    for (int n4 = 0; n4 < 4; ++n4) {                                           \
      int rr = wn * 128 + ((nh_) * 4 + n4) * 16 + l15;                         \
      bfq[n4] = *(const bf16x8*)(BsB + ((rr*128 + (kk_)*64 + hi*16) ^ ((rr&7)<<4))); \
    }

#define MFMA_Q(kk_, nh_)                                                       \
    __builtin_amdgcn_s_setprio(1);                                             \
    _Pragma("unroll")                                                          \
    for (int m = 0; m < 4; ++m)                                                \
      _Pragma("unroll")                                                        \
      for (int n4 = 0; n4 < 4; ++n4)                                           \
        acc[m][(nh_)*4 + n4] = __builtin_amdgcn_mfma_f32_16x16x32_bf16(        \
            af[m], bfq[n4], acc[m][(nh_)*4 + n4], 0, 0, 0);                    \
    __builtin_amdgcn_s_setprio(0);

  // barrier, then wait own ds_reads (issued pre-barrier), then MFMA
#define PH_PRE                                                                 \
    __builtin_amdgcn_sched_barrier(0);                                         \
    __builtin_amdgcn_s_barrier();                                              \
    asm volatile("s_waitcnt lgkmcnt(0)" ::: "memory");                         \
    __builtin_amdgcn_sched_barrier(0);

#define PH_POST                                                                \
    __builtin_amdgcn_sched_barrier(0);                                         \
    __builtin_amdgcn_s_barrier();                                              \
    __builtin_amdgcn_sched_barrier(0);

  // One K-step: mfma buf mb_, stage buf sb_ = mb_^1.
  // Per-wave VM issue order: gll0..7 then x-load (newest) -> final vmcnt(1)
  // drains all B(kt+1) loads and keeps the x prefetch in flight.
#define BODY(kt_, mb_, sb_, XU_, XL_)                                          \
  {                                                                            \
    const char* AsB = lds + (mb_) * ABYTES;                                    \
    const char* BsB = lds + 32768 + (mb_) * BBYTES;                            \
    const int ktn = ((kt_) + 1 < NKT ? (kt_) + 1 : NKT - 1);                   \
    bf16x8 af[4], bfq[4];                                                      \
    uint pk[8];                                                                \
    /* P0 */                                                                   \
    ISSUE_B2(ktn, sb_, 0)                                                      \
    LOAD_AF(0) LOAD_BF(0, 0)                                                   \
    PH_PRE MFMA_Q(0, 0) PH_POST                                                \
    /* P1 */                                                                   \
    ISSUE_B2(ktn, sb_, 1)                                                      \
    LOAD_BF(0, 1)                                                              \
    PH_PRE MFMA_Q(0, 1) PH_POST                                                \
    /* P2 */                                                                   \
    ISSUE_B2(ktn, sb_, 2)                                                      \
    SINS_HALF(XU_, 0)                                                          \
    LOAD_AF(1) LOAD_BF(1, 0)                                                   \
    PH_PRE MFMA_Q(1, 0)                                                        \
    A_WRITE(0, sb_)                                                            \
    PH_POST                                                                    \
    /* P3 */                                                                   \
    ISSUE_B2(ktn, sb_, 3)                                                      \
    SINS_HALF(XU_, 1)                                                          \
    LOAD_BF(1, 1)                                                              \
    XL_ = xbase[((kt_) + 2 < NKT ? (kt_) + 2 : NKT - 1) * 4];                  \
    PH_PRE MFMA_Q(1, 1)                                                        \
    A_WRITE(1, sb_)                                                            \
    __builtin_amdgcn_sched_barrier(0);                                         \
    asm volatile("s_waitcnt vmcnt(1) lgkmcnt(0)" ::: "memory");                \
    __builtin_amdgcn_s_barrier();                                              \
    __builtin_amdgcn_sched_barrier(0);                                         \
  }

  // ---- prologue: x(0); B(0) glls; x(1); sins(x0)->A0; vmcnt(1) barrier ----
  float xs0, xs1;
  {
    float xp = xbase[0];
    __builtin_amdgcn_sched_barrier(0);
    ISSUE_B2(0, 0, 0) ISSUE_B2(0, 0, 1) ISSUE_B2(0, 0, 2) ISSUE_B2(0, 0, 3)
    __builtin_amdgcn_sched_barrier(0);
    xs1 = xbase[4];
    __builtin_amdgcn_sched_barrier(0);
    {
      uint pk[8];
      SINS_HALF(xp, 0)
      SINS_HALF(xp, 1)
      A_WRITE(0, 0)
      A_WRITE(1, 0)
    }
    __builtin_amdgcn_sched_barrier(0);
    asm volatile("s_waitcnt vmcnt(1) lgkmcnt(0)" ::: "memory");
    __builtin_amdgcn_s_barrier();
    __builtin_amdgcn_sched_barrier(0);
  }

  for (int kt = 0; kt < NKT; kt += 2) {
    BODY(kt,     0, 1, xs1, xs0)
    BODY(kt + 1, 1, 0, xs0, xs1)
  }

  // ---- epilogue: y = acc + offs[o] ----
#pragma unroll
  for (int n = 0; n < 8; ++n) {
    int col = wn * 128 + n * 16 + l15;
    float off = offs[col];
#pragma unroll
    for (int m = 0; m < 4; ++m) {
      int row = row0 + wm * 64 + m * 16 + hi * 4;
      float* op = out + (size_t)row * NOUT + col;
#pragma unroll
      for (int j = 0; j < 4; ++j)
        op[(size_t)j * NOUT] = acc[m][n][j] + off;
    }
  }
}

// ---------------------------------------------------------------------------
extern "C" void kernel_launch(void* const* d_in, const int* in_sizes, int n_in,
                              void* d_out, int out_size, void* d_ws, size_t ws_size,
                              hipStream_t stream) {
  const float* x       = (const float*)d_in[0];
  const float* omega   = (const float*)d_in[1];
  const float* phase   = (const float*)d_in[2];
  const float* c_basis = (const float*)d_in[3];
  const float* bias    = (const float*)d_in[4];
  float* out = (float*)d_out;

  float*  offs = (float*)d_ws;
  ushort* cb   = (ushort*)((char*)d_ws + 2048);

  hipFuncSetAttribute((const void*)gemm_kernel,
                      hipFuncAttributeMaxDynamicSharedMemorySize, 163840);

  prep_kernel<<<NOUT, 256, 0, stream>>>(omega, phase, c_basis, bias, cb, offs);
  gemm_kernel<<<BATCH / BM, 512, 163840, stream>>>(x, omega, phase, cb, offs, out);
}

// Round 7
// 131.900 us; speedup vs baseline: 1.1003x; 1.1003x over previous
//
#include <hip/hip_runtime.h>
#include <hip/hip_bf16.h>

// SineLayer: y[b,o] = sum_{i,d} sin(w_d*x[b,i]+p_d) * (scale_d*c[o,i,d]) + offs[o]
// GEMM: M=32768, N=512, K=4096, bf16 MFMA 16x16x32.
// R7: R5 structure (1 barrier/kt, counted vmcnt(1)) with scheduling freedom:
// sins computed into registers with NO fences around the MFMA cluster, A-writes
// sunk to end of iteration -> compiler interleaves VALU/trans into MFMA gaps.

#define BATCH 32768
#define NIN   256
#define NOUT  512
#define DDIM  16
#define BM    128
#define BN    512
#define BK    64
#define NKT   ((NIN*DDIM)/BK)     // 64 K-steps
#define TILE_BYTES (BN*BK*2)      // 64 KB per kt pre-swizzled B tile
#define ABYTES (BM*BK*2)          // 16 KB per A buffer
#define BBYTES (BN*BK*2)          // 64 KB per B buffer
#define EPSV  1e-8f
#define INV2PI 0.15915494309189535f

typedef short  bf16x8 __attribute__((ext_vector_type(8)));
typedef float  f32x4  __attribute__((ext_vector_type(4)));

static __device__ __forceinline__ ushort f2bf(float f) {
  union { __hip_bfloat16 h; ushort u; } cv;
  cv.h = __float2bfloat16(f);
  return cv.u;
}

static __device__ __forceinline__ float sgpr_f(float v) {
  return __builtin_bit_cast(float,
      __builtin_amdgcn_readfirstlane(__builtin_bit_cast(int, v)));
}

// ---------------------------------------------------------------------------
// Prep: cb[o,k] = bf16(scale_d * c[o,i,d]) as ONE pre-swizzled 512x64 tile per
// kt (byte = (r*128 + kloc*2) ^ ((r&7)<<4), r = o) so a LINEAR global_load_lds
// copy yields the swizzled LDS image. offs[o] = bias[o] + sum mu*scale*c.
// ---------------------------------------------------------------------------
__global__ __launch_bounds__(256) void prep_kernel(
    const float* __restrict__ omega, const float* __restrict__ phase,
    const float* __restrict__ c_basis, const float* __restrict__ bias,
    ushort* __restrict__ cb, float* __restrict__ offs)
{
  __shared__ float s_scale[DDIM];
  __shared__ float s_musc[DDIM];
  __shared__ float s_red[4];

  const int o = blockIdx.x;
  const int t = threadIdx.x;

  if (t < DDIM) {
    float w = omega[t];
    float p = phase[t];
    float mu  = expf(-0.5f * w * w) * sinf(p);
    float var = 0.5f * (1.0f - expf(-2.0f * w * w) * cosf(2.0f * p)) - mu * mu;
    float sd  = sqrtf(fmaxf(var, 0.0f));
    float sc  = 1.0f / (sd + EPSV);
    s_scale[t] = sc;
    s_musc[t]  = mu * sc;
  }
  __syncthreads();

  const float* cp = c_basis + ((size_t)o * NIN + t) * DDIM;
  float cv[DDIM];
  {
    const float4* cp4 = (const float4*)cp;
    float4 a = cp4[0], b = cp4[1], c = cp4[2], d = cp4[3];
    cv[0]=a.x; cv[1]=a.y; cv[2]=a.z; cv[3]=a.w;
    cv[4]=b.x; cv[5]=b.y; cv[6]=b.z; cv[7]=b.w;
    cv[8]=c.x; cv[9]=c.y; cv[10]=c.z; cv[11]=c.w;
    cv[12]=d.x; cv[13]=d.y; cv[14]=d.z; cv[15]=d.w;
  }

  float partial = 0.0f;
  uint pk[8];
#pragma unroll
  for (int d = 0; d < DDIM; d += 2) {
    partial += cv[d] * s_musc[d] + cv[d+1] * s_musc[d+1];
    ushort u0 = f2bf(cv[d]   * s_scale[d]);
    ushort u1 = f2bf(cv[d+1] * s_scale[d+1]);
    pk[d >> 1] = (uint)u0 | ((uint)u1 << 16);
  }

  {
    const int r   = o;               // 0..511
    const int kt  = t >> 2;
    const int swz = (r & 7) << 4;
    char* tile = (char*)cb + (size_t)kt * TILE_BYTES;
    int b0 = r * 128 + (t & 3) * 32;
    *(uint4*)(tile + ((b0     ) ^ swz)) = make_uint4(pk[0], pk[1], pk[2], pk[3]);
    *(uint4*)(tile + ((b0 + 16) ^ swz)) = make_uint4(pk[4], pk[5], pk[6], pk[7]);
  }

#pragma unroll
  for (int off = 32; off > 0; off >>= 1) partial += __shfl_down(partial, off, 64);
  if ((t & 63) == 0) s_red[t >> 6] = partial;
  __syncthreads();
  if (t == 0) offs[o] = bias[o] + s_red[0] + s_red[1] + s_red[2] + s_red[3];
}

// ---------------------------------------------------------------------------
// GEMM: 128x512 tile, BK=64, 512 threads (8 waves: 2m x 4n, wave = 64x128).
// LDS: A0[16K] A1[16K] B0[64K] B1[64K] = 160 KB. Per iter:
//   ISSUE_B(kt+1); x-load(kt+2); sins->pk; MFMA(kt) [interleaved by compiler];
//   A-writes(kt+1); vmcnt(1)+lgkmcnt(0) barrier.
// ---------------------------------------------------------------------------
__global__ __launch_bounds__(512, 2) void gemm_kernel(
    const float* __restrict__ x, const float* __restrict__ omega,
    const float* __restrict__ phase, const ushort* __restrict__ cb,
    const float* __restrict__ offs, float* __restrict__ out)
{
  extern __shared__ char lds[];

  const int t    = threadIdx.x;
  const int lane = t & 63;
  const int wid  = t >> 6;
  const int wm   = wid >> 2;       // 0..1
  const int wn   = wid & 3;        // 0..3
  const int row0 = blockIdx.x * BM;

  // uniform omega/phase in SGPRs (readfirstlane) -> zero VGPR cost
  float wv[DDIM], pv[DDIM];
#pragma unroll
  for (int d = 0; d < DDIM; ++d) {
    wv[d] = sgpr_f(omega[d] * INV2PI);
    pv[d] = sgpr_f(phase[d] * INV2PI);
  }

  f32x4 acc[4][8];
#pragma unroll
  for (int m = 0; m < 4; ++m)
#pragma unroll
    for (int n = 0; n < 8; ++n) acc[m][n] = (f32x4){0.f, 0.f, 0.f, 0.f};

  // A staging: thread t -> row t>>2 (0..127), i-slot t&3; 1 x -> 16 sins
  const int arow = t >> 2;
  const int acol = t & 3;
  const float* xbase = x + (size_t)(row0 + arow) * NIN + acol;
  const int aswz = (arow & 7) << 4;
  const int ab0  = arow * 128 + acol * 32;

  const int hi  = lane >> 4;       // 0..3
  const int l15 = lane & 15;

#define GLL(s_, d_) __builtin_amdgcn_global_load_lds(                          \
      (const __attribute__((address_space(1))) void*)(s_),                     \
      (__attribute__((address_space(3))) void*)(d_), 16, 0, 0)

  // 8 global_load_lds: 64 KB B-tile kt_ -> B buffer sb_ (compile-time sb_)
#define ISSUE_B(kt_, sb_)                                                      \
  {                                                                            \
    const char* src = (const char*)cb + (size_t)(kt_) * TILE_BYTES             \
                      + wid * 8192 + lane * 16;                                \
    char* dst = lds + 32768 + (sb_) * BBYTES + wid * 8192;                     \
    GLL(src, dst);                 GLL(src + 1024, dst + 1024);                \
    GLL(src + 2048, dst + 2048);   GLL(src + 3072, dst + 3072);                \
    GLL(src + 4096, dst + 4096);   GLL(src + 5120, dst + 5120);                \
    GLL(src + 6144, dst + 6144);   GLL(src + 7168, dst + 7168);                \
  }

  // 16 sins -> 8 packed bf16-pair words in pk[] (pure VALU/trans, no stores)
#define SINS_ALL(xx_)                                                          \
    _Pragma("unroll")                                                          \
    for (int d = 0; d < DDIM; d += 2) {                                        \
      float s0 = __builtin_amdgcn_sinf(fmaf(wv[d],   (xx_), pv[d]));           \
      float s1 = __builtin_amdgcn_sinf(fmaf(wv[d+1], (xx_), pv[d+1]));         \
      uint u0 = __builtin_bit_cast(uint, s0) + 0x8000u;                        \
      uint u1 = __builtin_bit_cast(uint, s1) + 0x8000u;                        \
      pk[d >> 1] = __builtin_amdgcn_perm(u1, u0, 0x07060302u);                 \
    }

  // two swizzled ds_write_b128 of the packed sins into A buffer sb_
#define A_WRITE2(sb_)                                                          \
    *(uint4*)(lds + (sb_) * ABYTES + ((ab0     ) ^ aswz)) =                    \
        make_uint4(pk[0], pk[1], pk[2], pk[3]);                                \
    *(uint4*)(lds + (sb_) * ABYTES + ((ab0 + 16) ^ aswz)) =                    \
        make_uint4(pk[4], pk[5], pk[6], pk[7]);

  // B-fragments loaded in 4-reg chunks (peak regs: af 16 + bfr 16)
#define MFMA_STEP(mb_)                                                         \
  {                                                                            \
    const char* AsB = lds + (mb_) * ABYTES;                                    \
    const char* BsB = lds + 32768 + (mb_) * BBYTES;                            \
    __builtin_amdgcn_s_setprio(1);                                             \
    _Pragma("unroll")                                                          \
    for (int kk = 0; kk < 2; ++kk) {                                           \
      bf16x8 af[4];                                                            \
      _Pragma("unroll")                                                        \
      for (int m = 0; m < 4; ++m) {                                            \
        int rr = wm * 64 + m * 16 + l15;                                       \
        af[m] = *(const bf16x8*)(AsB + ((rr*128 + kk*64 + hi*16) ^ ((rr&7)<<4))); \
      }                                                                        \
      _Pragma("unroll")                                                        \
      for (int nh = 0; nh < 2; ++nh) {                                         \
        bf16x8 bfr[4];                                                         \
        _Pragma("unroll")                                                      \
        for (int n4 = 0; n4 < 4; ++n4) {                                       \
          int rr = wn * 128 + (nh * 4 + n4) * 16 + l15;                        \
          bfr[n4] = *(const bf16x8*)(BsB + ((rr*128 + kk*64 + hi*16) ^ ((rr&7)<<4))); \
        }                                                                      \
        _Pragma("unroll")                                                      \
        for (int m = 0; m < 4; ++m)                                            \
          _Pragma("unroll")                                                    \
          for (int n4 = 0; n4 < 4; ++n4)                                       \
            acc[m][nh * 4 + n4] = __builtin_amdgcn_mfma_f32_16x16x32_bf16(     \
                af[m], bfr[n4], acc[m][nh * 4 + n4], 0, 0, 0);                 \
      }                                                                        \
    }                                                                          \
    __builtin_amdgcn_s_setprio(0);                                             \
  }

#define CBAR(vm_)                                                              \
  __builtin_amdgcn_sched_barrier(0);                                           \
  asm volatile("s_waitcnt vmcnt(" #vm_ ") lgkmcnt(0)" ::: "memory");           \
  __builtin_amdgcn_s_barrier();                                                \
  __builtin_amdgcn_sched_barrier(0);

  // One iter: mfma buf mb_, stage buf sb_=mb_^1; sins for slice kt_+1 (XU_),
  // x prefetch for slice kt_+2 (XL_). No fences between sins/MFMA/A-writes.
#define BODY(kt_, mb_, sb_, XU_, XL_)                                          \
  {                                                                            \
    ISSUE_B(((kt_) + 1 < NKT ? (kt_) + 1 : NKT - 1), sb_);                     \
    __builtin_amdgcn_sched_barrier(0);                                         \
    XL_ = xbase[((kt_) + 2 < NKT ? (kt_) + 2 : NKT - 1) * 4];                  \
    __builtin_amdgcn_sched_barrier(0);                                         \
    uint pk[8];                                                                \
    SINS_ALL(XU_)                                                              \
    MFMA_STEP(mb_)                                                             \
    A_WRITE2(sb_)                                                              \
    CBAR(1)                                                                    \
  }

  // ---- prologue ----
  float xs0, xs1;
  {
    float xp = xbase[0];
    __builtin_amdgcn_sched_barrier(0);
    ISSUE_B(0, 0);
    __builtin_amdgcn_sched_barrier(0);
    xs1 = xbase[4];
    __builtin_amdgcn_sched_barrier(0);
    {
      uint pk[8];
      SINS_ALL(xp)
      A_WRITE2(0)
    }
    CBAR(1)                       // drains B(0)+x(0), keeps xs1 in flight
  }

  for (int kt = 0; kt < NKT; kt += 2) {
    BODY(kt,     0, 1, xs1, xs0)
    BODY(kt + 1, 1, 0, xs0, xs1)
  }

  // ---- epilogue: y = acc + offs[o] ----
#pragma unroll
  for (int n = 0; n < 8; ++n) {
    int col = wn * 128 + n * 16 + l15;
    float off = offs[col];
#pragma unroll
    for (int m = 0; m < 4; ++m) {
      int row = row0 + wm * 64 + m * 16 + hi * 4;
      float* op = out + (size_t)row * NOUT + col;
#pragma unroll
      for (int j = 0; j < 4; ++j)
        op[(size_t)j * NOUT] = acc[m][n][j] + off;
    }
  }
}

// ---------------------------------------------------------------------------
extern "C" void kernel_launch(void* const* d_in, const int* in_sizes, int n_in,
                              void* d_out, int out_size, void* d_ws, size_t ws_size,
                              hipStream_t stream) {
  const float* x       = (const float*)d_in[0];
  const float* omega   = (const float*)d_in[1];
  const float* phase   = (const float*)d_in[2];
  const float* c_basis = (const float*)d_in[3];
  const float* bias    = (const float*)d_in[4];
  float* out = (float*)d_out;

  float*  offs = (float*)d_ws;
  ushort* cb   = (ushort*)((char*)d_ws + 2048);

  hipFuncSetAttribute((const void*)gemm_kernel,
                      hipFuncAttributeMaxDynamicSharedMemorySize, 163840);

  prep_kernel<<<NOUT, 256, 0, stream>>>(omega, phase, c_basis, bias, cb, offs);
  gemm_kernel<<<BATCH / BM, 512, 163840, stream>>>(x, omega, phase, cb, offs, out);
}